// Round 2
// baseline (362.040 us; speedup 1.0000x reference)
//
#include <hip/hip_runtime.h>
#include <hip/hip_bf16.h>

// Event-camera simulator: per-pixel independent scan over T frames.
// One thread per pixel, fully unrolled t-loop.
// R2: prefetch ALL global loads up front and pin them with empty asm so the
// compiler cannot sink them into the loop (R1 showed VGPR=36 => loads were
// sunk, exposing ~39 serial global-load latencies; dur 126us, VALUBusy 33%).
// __launch_bounds__(256,4): allow up to 128 VGPRs (4 waves/EU), no spill.

namespace {
constexpr int Bc = 4, Hc = 480, Wc = 640, Tc = 32;
constexpr int HW  = Hc * Wc;     // 307200
constexpr int BHW = Bc * HW;     // 1228800
}

__device__ __forceinline__ float rfl(float x) {
    // wave-uniform value -> SGPR (b is uniform per wave: 64 | HW)
    return __uint_as_float(__builtin_amdgcn_readfirstlane(__float_as_uint(x)));
}

__global__ __launch_bounds__(256, 4) void event_sim_kernel(
    const float* __restrict__ log_images,    // (H, W, B*T)
    const float* __restrict__ image_ts,      // (B, T)
    const float* __restrict__ first_times,   // (B,)
    const float* __restrict__ thresholds,    // (2, B, H, W)
    const float* __restrict__ log_states,    // (B, H, W)
    const float* __restrict__ timestamps,    // (B, H, W)
    const float* __restrict__ prev_image_ts, // (B,)
    const float* __restrict__ refractory,    // (B,)
    const float* __restrict__ leak_rates,    // (B,)
    const float* __restrict__ shot_rates,    // (B,)
    const float* __restrict__ threshold_mus, // (B, 2)
    const float* __restrict__ rng,           // (T, B, H, W)
    float* __restrict__ out)                 // (B, H, W)
{
#pragma clang fp contract(off)
    const int idx = blockIdx.x * 256 + threadIdx.x;
    const int b = idx / HW;
    const int p = idx - b * HW;   // h*W + w

    // ================= issue EVERY load up front (max MLP) =================
    // frames: per-pixel T=32 floats are contiguous (128 B) -> 8 dwordx4
    const float4* fr4 = reinterpret_cast<const float4*>(log_images)
                        + ((size_t)p * Bc + b) * (Tc / 4);
    float4 f4[Tc / 4];
#pragma unroll
    for (int i = 0; i < Tc / 4; ++i) f4[i] = fr4[i];

    // rng rows t=1..31: coalesced dword loads
    const float* rng_base = rng + idx;
    float us[Tc - 1];
#pragma unroll
    for (int t = 1; t < Tc; ++t) us[t - 1] = rng_base[(size_t)t * BHW];

    const float th_off = thresholds[idx];          // (0,b,h,w)
    const float th_on  = thresholds[BHW + idx];    // (1,b,h,w)

    // pin everything: forbid the scheduler from sinking the loads
#pragma unroll
    for (int i = 0; i < Tc / 4; ++i)
        asm volatile("" : "+v"(f4[i].x), "+v"(f4[i].y), "+v"(f4[i].z), "+v"(f4[i].w));
#pragma unroll
    for (int i = 0; i < Tc - 1; ++i)
        asm volatile("" : "+v"(us[i]));
    {
        float a = th_off, c = th_on;
        asm volatile("" : "+v"(a), "+v"(c));
    }

    float fs[Tc];
#pragma unroll
    for (int i = 0; i < Tc / 4; ++i) {
        fs[4*i+0] = f4[i].x; fs[4*i+1] = f4[i].y;
        fs[4*i+2] = f4[i].z; fs[4*i+3] = f4[i].w;
    }

    // ---- per-b scalars (wave-uniform -> SGPRs) ----
    const float4* ts4 = reinterpret_cast<const float4*>(image_ts) + b * (Tc / 4);
    float tss[Tc];
#pragma unroll
    for (int i = 0; i < Tc / 4; ++i) {
        float4 v = ts4[i];
        tss[4*i+0] = rfl(v.x); tss[4*i+1] = rfl(v.y);
        tss[4*i+2] = rfl(v.z); tss[4*i+3] = rfl(v.w);
    }

    const float ref   = rfl(refractory[b]);
    const float leak  = rfl(leak_rates[b]);
    const float shot  = rfl(shot_rates[b]);
    const float mu_on = rfl(threshold_mus[2*b + 1]);
    const bool  ft    = rfl(first_times[b]) > 0.0f;
    const float pv    = rfl(prev_image_ts[b]);

    float state, last, ts0;
    if (ft) {                       // wave-uniform branch: skip 2 loads
        state = fs[0];
        ts0   = tss[0];
        last  = ts0 - ref;
    } else {
        state = log_states[idx];
        ts0   = pv;
        last  = timestamps[idx];
    }
    float counts  = 0.0f;
    float ts_prev = ts0;

#pragma unroll
    for (int t = 1; t < Tc; ++t) {
        const float ts_t = tss[t];
        const float u    = us[t - 1];
        const float dt   = ts_t - ts_prev;

        // state leak: state - ((leak*dt)*mu_on)  (reference association)
        state = state - ((leak * dt) * mu_on);

        const float diff = fs[t] - state;
        const bool  pos  = diff >= 0.0f;
        const float th   = pos ? th_on : th_off;
        float n = floorf(fabsf(diff) / th);            // IEEE div + exact floor
        const bool okb = (ts_t - last) >= ref;
        n = okb ? n : 0.0f;
        const float pn = pos ? n : -n;                 // pol * n
        state  = state + (pn * th);                    // (pol*n)*th
        counts = counts + pn;
        last   = (n > 0.0f) ? ts_t : last;

        // shot noise (uses UPDATED last, per reference ordering)
        const float pshot   = shot * dt;
        const bool  is_shot = (u < pshot) && ((ts_t - last) >= ref);
        const float pol_s   = (u < (0.5f * pshot)) ? 1.0f : -1.0f;
        counts = is_shot ? (counts + pol_s) : counts;
        last   = is_shot ? ts_t : last;

        ts_prev = ts_t;
    }

    out[idx] = counts;
}

extern "C" void kernel_launch(void* const* d_in, const int* in_sizes, int n_in,
                              void* d_out, int out_size, void* d_ws, size_t ws_size,
                              hipStream_t stream) {
    const float* log_images    = (const float*)d_in[0];
    // d_in[1] = video_len (int64) — unused by the reference computation
    const float* image_ts      = (const float*)d_in[2];
    const float* first_times   = (const float*)d_in[3];
    const float* thresholds    = (const float*)d_in[4];
    const float* log_states    = (const float*)d_in[5];
    const float* timestamps    = (const float*)d_in[6];
    const float* prev_image_ts = (const float*)d_in[7];
    const float* refractory    = (const float*)d_in[8];
    const float* leak_rates    = (const float*)d_in[9];
    const float* shot_rates    = (const float*)d_in[10];
    const float* threshold_mus = (const float*)d_in[11];
    const float* rng           = (const float*)d_in[12];
    float* out = (float*)d_out;

    dim3 grid(BHW / 256);
    dim3 block(256);
    hipLaunchKernelGGL(event_sim_kernel, grid, block, 0, stream,
                       log_images, image_ts, first_times, thresholds,
                       log_states, timestamps, prev_image_ts, refractory,
                       leak_rates, shot_rates, threshold_mus, rng, out);
}

// Round 5
// 360.425 us; speedup vs baseline: 1.0045x; 1.0045x over previous
//
#include <hip/hip_runtime.h>
#include <hip/hip_bf16.h>

// Event-camera simulator: per-pixel independent scan over T frames.
// R5 = R3 resubmitted again (R3/R4 both hit GPU-acquisition timeouts; the
// explicit-burst kernel has never been benched).
// R3 rationale: R2 post-mortem showed empty-asm pins were sunk into the loop
// together with the loads (VGPR=44 proved <65 values ever live), so ~40
// global-load latencies stayed serialized (dur 127us, VALUBusy 33%).
// Now every load is an explicit volatile-asm global_load (totally ordered
// among volatile asm), then ONE s_waitcnt vmcnt(0) + sched_barrier(0)
// (rule #18) before the compute. Addresses: SGPR base + 32-bit voffset,
// offset: immediates for the 8 frame loads.

namespace {
constexpr int Bc = 4, Hc = 480, Wc = 640, Tc = 32;
constexpr int HW  = Hc * Wc;     // 307200
constexpr int BHW = Bc * HW;     // 1228800
}

typedef float v4f __attribute__((ext_vector_type(4)));

__device__ __forceinline__ float rfl(float x) {
    // wave-uniform value -> SGPR (b is uniform per wave: 64 | HW)
    return __uint_as_float(__builtin_amdgcn_readfirstlane(__float_as_uint(x)));
}

__global__ __launch_bounds__(256, 4) void event_sim_kernel(
    const float* __restrict__ log_images,    // (H, W, B*T)
    const float* __restrict__ image_ts,      // (B, T)
    const float* __restrict__ first_times,   // (B,)
    const float* __restrict__ thresholds,    // (2, B, H, W)
    const float* __restrict__ log_states,    // (B, H, W)
    const float* __restrict__ timestamps,    // (B, H, W)
    const float* __restrict__ prev_image_ts, // (B,)
    const float* __restrict__ refractory,    // (B,)
    const float* __restrict__ leak_rates,    // (B,)
    const float* __restrict__ shot_rates,    // (B,)
    const float* __restrict__ threshold_mus, // (B, 2)
    const float* __restrict__ rng,           // (T, B, H, W)
    float* __restrict__ out)                 // (B, H, W)
{
#pragma clang fp contract(off)
    const int idx = blockIdx.x * 256 + threadIdx.x;
    const int b = idx / HW;
    const int p = idx - b * HW;   // h*W + w

    // ============== burst-issue EVERY global load (41 VMEM ops) ==============
    // frames: pixel's 32 floats contiguous (128 B, aligned) at (p*Bc+b)*128
    const uint32_t fr_off = (uint32_t)(p * Bc + b) * (uint32_t)(Tc * 4);
    v4f f4[Tc / 4];
#define LDF(i, OFF)                                                     \
    asm volatile("global_load_dwordx4 %0, %1, %2 offset:" OFF           \
                 : "=v"(f4[i]) : "v"(fr_off), "s"(log_images))
    LDF(0, "0");  LDF(1, "16"); LDF(2, "32"); LDF(3, "48");
    LDF(4, "64"); LDF(5, "80"); LDF(6, "96"); LDF(7, "112");
#undef LDF

    const uint32_t u_off = (uint32_t)idx * 4u;

    // thresholds (0,b,h,w) and (1,b,h,w)
    float th_off, th_on;
    asm volatile("global_load_dword %0, %1, %2"
                 : "=v"(th_off) : "v"(u_off), "s"(thresholds));
    asm volatile("global_load_dword %0, %1, %2"
                 : "=v"(th_on) : "v"(u_off + (uint32_t)(BHW * 4)), "s"(thresholds));

    // rng rows t=1..31 (coalesced; plane stride BHW*4 bytes)
    float us[Tc - 1];
#pragma unroll
    for (int t = 1; t < Tc; ++t) {
        asm volatile("global_load_dword %0, %1, %2"
                     : "=v"(us[t - 1])
                     : "v"(u_off + (uint32_t)t * (uint32_t)(BHW * 4)), "s"(rng));
    }

    // one wait for the whole burst; fence so no consumer is hoisted above it
    asm volatile("s_waitcnt vmcnt(0)" ::: "memory");
    __builtin_amdgcn_sched_barrier(0);
    // ========================================================================

    float fs[Tc];
#pragma unroll
    for (int i = 0; i < Tc / 4; ++i) {
        fs[4*i+0] = f4[i][0]; fs[4*i+1] = f4[i][1];
        fs[4*i+2] = f4[i][2]; fs[4*i+3] = f4[i][3];
    }

    // ---- per-b scalars (wave-uniform -> SGPRs); once per wave, cheap ----
    const float4* ts4 = reinterpret_cast<const float4*>(image_ts) + b * (Tc / 4);
    float tss[Tc];
#pragma unroll
    for (int i = 0; i < Tc / 4; ++i) {
        float4 v = ts4[i];
        tss[4*i+0] = rfl(v.x); tss[4*i+1] = rfl(v.y);
        tss[4*i+2] = rfl(v.z); tss[4*i+3] = rfl(v.w);
    }

    const float ref   = rfl(refractory[b]);
    const float leak  = rfl(leak_rates[b]);
    const float shot  = rfl(shot_rates[b]);
    const float mu_on = rfl(threshold_mus[2*b + 1]);
    const bool  ft    = rfl(first_times[b]) > 0.0f;
    const float pv    = rfl(prev_image_ts[b]);

    float state, last, ts0;
    if (ft) {                       // wave-uniform branch: skip 2 loads
        state = fs[0];
        ts0   = tss[0];
        last  = ts0 - ref;
    } else {
        state = log_states[idx];
        ts0   = pv;
        last  = timestamps[idx];
    }
    float counts  = 0.0f;
    float ts_prev = ts0;

#pragma unroll
    for (int t = 1; t < Tc; ++t) {
        const float ts_t = tss[t];
        const float u    = us[t - 1];
        const float dt   = ts_t - ts_prev;

        // state leak: state - ((leak*dt)*mu_on)  (reference association)
        state = state - ((leak * dt) * mu_on);

        const float diff = fs[t] - state;
        const bool  pos  = diff >= 0.0f;
        const float th   = pos ? th_on : th_off;
        float n = floorf(fabsf(diff) / th);            // IEEE div + exact floor
        const bool okb = (ts_t - last) >= ref;
        n = okb ? n : 0.0f;
        const float pn = pos ? n : -n;                 // pol * n
        state  = state + (pn * th);                    // (pol*n)*th
        counts = counts + pn;
        last   = (n > 0.0f) ? ts_t : last;

        // shot noise (uses UPDATED last, per reference ordering)
        const float pshot   = shot * dt;
        const bool  is_shot = (u < pshot) && ((ts_t - last) >= ref);
        const float pol_s   = (u < (0.5f * pshot)) ? 1.0f : -1.0f;
        counts = is_shot ? (counts + pol_s) : counts;
        last   = is_shot ? ts_t : last;

        ts_prev = ts_t;
    }

    out[idx] = counts;
}

extern "C" void kernel_launch(void* const* d_in, const int* in_sizes, int n_in,
                              void* d_out, int out_size, void* d_ws, size_t ws_size,
                              hipStream_t stream) {
    const float* log_images    = (const float*)d_in[0];
    // d_in[1] = video_len (int64) — unused by the reference computation
    const float* image_ts      = (const float*)d_in[2];
    const float* first_times   = (const float*)d_in[3];
    const float* thresholds    = (const float*)d_in[4];
    const float* log_states    = (const float*)d_in[5];
    const float* timestamps    = (const float*)d_in[6];
    const float* prev_image_ts = (const float*)d_in[7];
    const float* refractory    = (const float*)d_in[8];
    const float* leak_rates    = (const float*)d_in[9];
    const float* shot_rates    = (const float*)d_in[10];
    const float* threshold_mus = (const float*)d_in[11];
    const float* rng           = (const float*)d_in[12];
    float* out = (float*)d_out;

    dim3 grid(BHW / 256);
    dim3 block(256);
    hipLaunchKernelGGL(event_sim_kernel, grid, block, 0, stream,
                       log_images, image_ts, first_times, thresholds,
                       log_states, timestamps, prev_image_ts, refractory,
                       leak_rates, shot_rates, threshold_mus, rng, out);
}